// Round 8
// baseline (181.400 us; speedup 1.0000x reference)
//
#include <hip/hip_runtime.h>
#include <math.h>

#define CIN 64
#define NP 128

typedef float f32x4 __attribute__((ext_vector_type(4)));
typedef short s16x8 __attribute__((ext_vector_type(8)));

union FragU { s16x8 v; unsigned u[4]; };

static __device__ __forceinline__ unsigned short f2b(float f) {
    unsigned u = __builtin_bit_cast(unsigned, f);
    unsigned r = (u + 0x7FFFu + ((u >> 16) & 1u)) >> 16;   // RNE (proven R1/R2/R5)
    return (unsigned short)r;
}
static __device__ __forceinline__ float b2f(unsigned short h) {
    unsigned u = ((unsigned)h) << 16;
    return __builtin_bit_cast(float, u);
}
// pack two f32 -> bf16x2 word (lo in low half), software RNE — NOT v_cvt_pk
// (R6 post-mortem: raw v_cvt_pk_bf16_f32 does not match RNE; absmax 17x worse)
static __device__ __forceinline__ unsigned pack2(float lo, float hi) {
    return (unsigned)f2b(lo) | ((unsigned)f2b(hi) << 16);
}

// K0: pack W_k, W_v (rows 128..383 of Wqkv) into bf16 MFMA A-fragment tiles.
__global__ __launch_bounds__(256) void prep_w(const float* __restrict__ Wqkv,
                                              unsigned short* __restrict__ Wb) {
    int e0 = (blockIdx.x * 256 + threadIdx.x) * 8;   // < 16384
    int lane = (e0 >> 3) & 63;
    int kc = (e0 >> 9) & 1;
    int t = e0 >> 10;
    int row = 128 + t * 16 + (lane & 15);
    int c0 = kc * 32 + (lane >> 4) * 8;
    for (int j = 0; j < 8; ++j)
        Wb[e0 + j] = f2b(Wqkv[row * 64 + c0 + j]);
}

// K1: fused kv-projection (MFMA) + exp + context accumulation (MFMA).
// Direct global->B-fragment loads (no X staging, no main-loop barriers).
__global__ __launch_bounds__(256, 3) void lin_attn_ctx(
    const float* __restrict__ x, const unsigned short* __restrict__ Wb,
    float* __restrict__ P, int n, int nch)
{
    __shared__ __align__(16) unsigned short EKVs[4][2560];  // 20 KiB: per-wave EK | V (80B rows)

    const int tid = threadIdx.x;
    const int l = tid & 63;
    const int w = tid >> 6;
    const int b = blockIdx.y;
    const int l15 = l & 15, lg = l >> 4;
    const uint4* Wb4 = (const uint4*)Wb;

    f32x4 zero4 = {0.f, 0.f, 0.f, 0.f};
    f32x4 ctx[4][2][2];
    float sacc[4][2][4];
#pragma unroll
    for (int h = 0; h < 4; ++h)
#pragma unroll
        for (int a = 0; a < 2; ++a) {
#pragma unroll
            for (int c2 = 0; c2 < 2; ++c2) ctx[h][a][c2] = zero4;
#pragma unroll
            for (int r = 0; r < 4; ++r) sacc[h][a][r] = 0.f;
        }

    const float* xw = x + (size_t)b * CIN * n;

    for (int ch = blockIdx.x; ch < nch; ch += gridDim.x) {
        // ---- direct global -> B-fragment loads, pack immediately (8-reg f32 transient) ----
        const float* xp = xw + ch * NP + w * 32 + l15;
        s16x8 bx[2][2];
#pragma unroll
        for (int pt = 0; pt < 2; ++pt)
#pragma unroll
            for (int kc = 0; kc < 2; ++kc) {
                float xv[8];
#pragma unroll
                for (int j = 0; j < 8; ++j)
                    xv[j] = xp[(size_t)(kc * 32 + lg * 8 + j) * n + pt * 16];
                FragU fu;
#pragma unroll
                for (int i = 0; i < 4; ++i)
                    fu.u[i] = pack2(xv[2 * i], xv[2 * i + 1]);
                bx[pt][kc] = fu.v;
            }

#pragma unroll
        for (int h = 0; h < 4; ++h) {
#pragma unroll
            for (int rt = 0; rt < 2; ++rt) {
                // W A-fragments (L1/L2-resident)
                s16x8 ak0 = *(const s16x8*)&Wb4[((2 * h + rt) * 2 + 0) * 64 + l];
                s16x8 ak1 = *(const s16x8*)&Wb4[((2 * h + rt) * 2 + 1) * 64 + l];
                s16x8 av0 = *(const s16x8*)&Wb4[((8 + 2 * h + rt) * 2 + 0) * 64 + l];
                s16x8 av1 = *(const s16x8*)&Wb4[((8 + 2 * h + rt) * 2 + 1) * 64 + l];
#pragma unroll
                for (int pt = 0; pt < 2; ++pt) {
                    f32x4 z = zero4;
                    z = __builtin_amdgcn_mfma_f32_16x16x32_bf16(ak0, bx[pt][0], z, 0, 0, 0);
                    z = __builtin_amdgcn_mfma_f32_16x16x32_bf16(ak1, bx[pt][1], z, 0, 0, 0);
                    f32x4 z2 = zero4;
                    z2 = __builtin_amdgcn_mfma_f32_16x16x32_bf16(av0, bx[pt][0], z2, 0, 0, 0);
                    z2 = __builtin_amdgcn_mfma_f32_16x16x32_bf16(av1, bx[pt][1], z2, 0, 0, 0);
                    // exp + restage to per-wave [row][pos] (80B-padded rows)
                    const int row0 = rt * 16 + lg * 4;
                    const int pos = pt * 16 + l15;
                    {
                        unsigned short e0 = f2b(__expf(z[0]));
                        unsigned short e1 = f2b(__expf(z[1]));
                        unsigned short e2 = f2b(__expf(z[2]));
                        unsigned short e3 = f2b(__expf(z[3]));
                        unsigned short* bp = &EKVs[w][row0 * 40 + pos];
                        bp[0]   = e0;
                        bp[40]  = e1;
                        bp[80]  = e2;
                        bp[120] = e3;
                        // accumulate the ROUNDED values (consistent with numerator operand)
                        sacc[h][rt][0] += b2f(e0);
                        sacc[h][rt][1] += b2f(e1);
                        sacc[h][rt][2] += b2f(e2);
                        sacc[h][rt][3] += b2f(e3);
                    }
                    {
                        unsigned short* bp = &EKVs[w][1280 + row0 * 40 + pos];
                        bp[0]   = f2b(z2[0]);
                        bp[40]  = f2b(z2[1]);
                        bp[80]  = f2b(z2[2]);
                        bp[120] = f2b(z2[3]);
                    }
                }
            }
            // context: C_h += EK (32xK32) @ V^T (K32x32)  (same-wave LDS, in-order DS pipe)
            s16x8 ea[2], vbf[2];
#pragma unroll
            for (int kt = 0; kt < 2; ++kt)
                ea[kt] = *(const s16x8*)&EKVs[w][(kt * 16 + l15) * 40 + lg * 8];
#pragma unroll
            for (int vt = 0; vt < 2; ++vt)
                vbf[vt] = *(const s16x8*)&EKVs[w][1280 + (vt * 16 + l15) * 40 + lg * 8];
#pragma unroll
            for (int kt = 0; kt < 2; ++kt)
#pragma unroll
                for (int vt = 0; vt < 2; ++vt)
                    ctx[h][kt][vt] = __builtin_amdgcn_mfma_f32_16x16x32_bf16(
                        ea[kt], vbf[vt], ctx[h][kt][vt], 0, 0, 0);
        }
    }

    // ---- cross-wave reduce, write per-block partials (EKVs aliased: 4224 of 5120 floats) ----
    float* Xf = (float*)&EKVs[0][0];
    float* Sf = Xf + 4096;
    float* Pb = P + (size_t)(b * gridDim.x + blockIdx.x) * 4224;
#pragma unroll
    for (int h = 0; h < 4; ++h) {
        __syncthreads();   // (h=0): all waves done with EKV reads; (h>0): done reading Xf
#pragma unroll
        for (int kt = 0; kt < 2; ++kt)
#pragma unroll
            for (int vt = 0; vt < 2; ++vt)
#pragma unroll
                for (int r = 0; r < 4; ++r) {
                    int d = kt * 16 + lg * 4 + r, e = vt * 16 + l15;
                    Xf[w * 1024 + d * 32 + e] = ctx[h][kt][vt][r];
                }
#pragma unroll
        for (int rt = 0; rt < 2; ++rt)
#pragma unroll
            for (int r = 0; r < 4; ++r) {
                float s = sacc[h][rt][r];
                s += __shfl_xor(s, 1); s += __shfl_xor(s, 2);
                s += __shfl_xor(s, 4); s += __shfl_xor(s, 8);
                if (l15 == 0) Sf[w * 32 + rt * 16 + lg * 4 + r] = s;
            }
        __syncthreads();
        for (int i = tid; i < 1024; i += 256)
            Pb[h * 1056 + i] = Xf[i] + Xf[1024 + i] + Xf[2048 + i] + Xf[3072 + i];
        if (tid < 32)
            Pb[h * 1056 + 1024 + tid] = Sf[tid] + Sf[32 + tid] + Sf[64 + tid] + Sf[96 + tid];
    }
}

// K2a: slot-sliced partial reduce: P[b][slot][4224] -> P2[b][16][4224]
__global__ __launch_bounds__(256) void reduce_p1(
    const float* __restrict__ P, float* __restrict__ P2, int nblk)
{
    const int idx = blockIdx.x * 256 + threadIdx.x;
    if (idx >= 4224) return;
    const int b = blockIdx.z, sz = blockIdx.y;
    float acc = 0.f;
    for (int slot = sz; slot < nblk; slot += 16)
        acc += P[((size_t)(b * nblk + slot)) * 4224 + idx];
    P2[((size_t)(b * 16 + sz)) * 4224 + idx] = acc;
}

// K2b: final reduce -> R[b][4224]
__global__ __launch_bounds__(256) void reduce_p2(
    const float* __restrict__ P2, float* __restrict__ R)
{
    const int idx = blockIdx.x * 256 + threadIdx.x;
    if (idx >= 4224) return;
    const int b = blockIdx.y;
    float acc = 0.f;
#pragma unroll
    for (int s = 0; s < 16; ++s)
        acc += P2[((size_t)(b * 16 + s)) * 4224 + idx];
    R[b * 4224 + idx] = acc;
}

// K3: build per-batch transposed 64x64 matrix Mt[c][o]
__global__ __launch_bounds__(256) void build_M(
    const float* __restrict__ R, const float* __restrict__ Wout,
    const float* __restrict__ Wqkv, float* __restrict__ Mt)
{
    __shared__ float ctx[4096];
    __shared__ float Ash[8192];
    const int b = blockIdx.x;
    const int tid = threadIdx.x;
    for (int i = tid; i < 4096; i += 256) {
        const int h = i >> 10, rr = i & 1023, d = rr >> 5, e = rr & 31;
        ctx[i] = R[b * 4224 + h * 1056 + d * 32 + e] /
                 R[b * 4224 + h * 1056 + 1024 + d];
    }
    __syncthreads();
    for (int i = tid; i < 8192; i += 256) {
        const int o = i >> 7, m = i & 127, h = m >> 5, d = m & 31;
        float acc = 0.f;
#pragma unroll
        for (int e = 0; e < 32; ++e)
            acc += Wout[o * 128 + h * 32 + e] * ctx[h * 1024 + d * 32 + e];
        Ash[i] = acc;
    }
    __syncthreads();
    const float scale = 0.17677669529663687f;
    for (int i = tid; i < 4096; i += 256) {
        const int o = i >> 6, c = i & 63;
        float acc = 0.f;
#pragma unroll
        for (int m = 0; m < 128; ++m)
            acc += Ash[o * 128 + m] * Wqkv[m * 64 + c];
        Mt[b * 4096 + c * 64 + o] = acc * scale;   // transposed store
    }
}

// K4: y[b,o,p] = sum_c Mt[c][o] x[b,c,p] + b_out[o]
__global__ __launch_bounds__(256, 4) void final_proj(
    const float* __restrict__ x, const float* __restrict__ Mt,
    const float* __restrict__ bout, float* __restrict__ y, int n)
{
    const int b = blockIdx.y;
    const int p = blockIdx.x * 256 + threadIdx.x;
    const float* xb = x + (size_t)b * CIN * n + p;
    const float* M = Mt + b * 4096;
    float acc[64];
#pragma unroll
    for (int o = 0; o < 64; ++o) acc[o] = bout[o];
    for (int c = 0; c < 64; ++c) {
        const float xv = xb[(size_t)c * n];
        const float* Mr = M + c * 64;
#pragma unroll
        for (int o = 0; o < 64; ++o) acc[o] += Mr[o] * xv;
    }
    float* yb = y + (size_t)b * CIN * n + p;
#pragma unroll
    for (int o = 0; o < 64; ++o) yb[(size_t)o * n] = acc[o];
}

extern "C" void kernel_launch(void* const* d_in, const int* in_sizes, int n_in,
                              void* d_out, int out_size, void* d_ws, size_t ws_size,
                              hipStream_t stream) {
    const float* x    = (const float*)d_in[0];
    const float* Wqkv = (const float*)d_in[1];
    const float* Wout = (const float*)d_in[2];
    const float* bout = (const float*)d_in[3];
    float* y = (float*)d_out;

    const int n = in_sizes[0] / 128;   // 110592
    const int nch = n / NP;            // 864

    // ws-adaptive partial-slot count
    int BLKX = 432;
    for (;;) {
        size_t need = 32768 + (size_t)2 * BLKX * 4224 * 4   // P
                    + (size_t)2 * 16 * 4224 * 4             // P2
                    + 2 * 4224 * 4 + 2 * 4096 * 4;          // R, Mt
        if (need <= ws_size || BLKX <= 64) break;
        BLKX = (BLKX == 432) ? 256 : (BLKX >> 1);
    }
    unsigned short* Wb = (unsigned short*)d_ws;                  // 32 KiB
    float* P  = (float*)((char*)d_ws + 32768);
    float* P2 = P + (size_t)2 * BLKX * 4224;
    float* R  = P2 + (size_t)2 * 16 * 4224;
    float* Mt = R + 2 * 4224;

    prep_w<<<8, 256, 0, stream>>>(Wqkv, Wb);
    lin_attn_ctx<<<dim3(BLKX, 2), 256, 0, stream>>>(x, Wb, P, n, nch);
    reduce_p1<<<dim3(17, 16, 2), 256, 0, stream>>>(P, P2, BLKX);
    reduce_p2<<<dim3(17, 2), 256, 0, stream>>>(P2, R);
    build_M<<<2, 256, 0, stream>>>(R, Wout, Wqkv, Mt);
    final_proj<<<dim3(n / 256, 2), 256, 0, stream>>>(x, Mt, bout, y, n);
}

// Round 9
// 147.113 us; speedup vs baseline: 1.2331x; 1.2331x over previous
//
#include <hip/hip_runtime.h>
#include <math.h>

#define CIN 64
#define NP 128

typedef float f32x4 __attribute__((ext_vector_type(4)));
typedef short s16x8 __attribute__((ext_vector_type(8)));

union FragU { s16x8 v; unsigned u[4]; };

static __device__ __forceinline__ unsigned short f2b(float f) {
    unsigned u = __builtin_bit_cast(unsigned, f);
    unsigned r = (u + 0x7FFFu + ((u >> 16) & 1u)) >> 16;   // RNE (proven R1/R2/R5/R8)
    return (unsigned short)r;
}
static __device__ __forceinline__ float b2f(unsigned short h) {
    unsigned u = ((unsigned)h) << 16;
    return __builtin_bit_cast(float, u);
}
// pack two f32 -> bf16x2 word, software RNE — NOT v_cvt_pk (R6: raw instr != RNE)
static __device__ __forceinline__ unsigned pack2(float lo, float hi) {
    return (unsigned)f2b(lo) | ((unsigned)f2b(hi) << 16);
}

// K0: pack W_k, W_v (rows 128..383 of Wqkv) into bf16 MFMA A-fragment tiles.
__global__ __launch_bounds__(256) void prep_w(const float* __restrict__ Wqkv,
                                              unsigned short* __restrict__ Wb) {
    int e0 = (blockIdx.x * 256 + threadIdx.x) * 8;   // < 16384
    int lane = (e0 >> 3) & 63;
    int kc = (e0 >> 9) & 1;
    int t = e0 >> 10;
    int row = 128 + t * 16 + (lane & 15);
    int c0 = kc * 32 + (lane >> 4) * 8;
    for (int j = 0; j < 8; ++j)
        Wb[e0 + j] = f2b(Wqkv[row * 64 + c0 + j]);
}

// K1: fused kv-projection (MFMA) + exp + context accumulation (MFMA).
// Direct global->B-fragment loads; no main-loop barriers.
// launch_bounds(256,2): 256-VGPR budget — R5/R8 post-mortem: the (256,3)
// 168-reg cap forced accumulator spill (VGPR 84, ~115MB/way scratch).
__global__ __launch_bounds__(256, 2) void lin_attn_ctx(
    const float* __restrict__ x, const unsigned short* __restrict__ Wb,
    float* __restrict__ P, int n, int nch)
{
    __shared__ __align__(16) unsigned short EKVs[4][2560];  // 20 KiB: per-wave EK | V (80B rows)

    const int tid = threadIdx.x;
    const int l = tid & 63;
    const int w = tid >> 6;
    const int b = blockIdx.y;
    const int l15 = l & 15, lg = l >> 4;
    const uint4* Wb4 = (const uint4*)Wb;

    f32x4 zero4 = {0.f, 0.f, 0.f, 0.f};
    f32x4 ctx[4][2][2];
    float sacc[4][2][4];
#pragma unroll
    for (int h = 0; h < 4; ++h)
#pragma unroll
        for (int a = 0; a < 2; ++a) {
#pragma unroll
            for (int c2 = 0; c2 < 2; ++c2) ctx[h][a][c2] = zero4;
#pragma unroll
            for (int r = 0; r < 4; ++r) sacc[h][a][r] = 0.f;
        }

    const float* xw = x + (size_t)b * CIN * n;

    for (int ch = blockIdx.x; ch < nch; ch += gridDim.x) {
        // ---- direct global -> B-fragment loads, pack immediately ----
        const float* xp = xw + ch * NP + w * 32 + l15;
        s16x8 bx[2][2];
#pragma unroll
        for (int pt = 0; pt < 2; ++pt)
#pragma unroll
            for (int kc = 0; kc < 2; ++kc) {
                float xv[8];
#pragma unroll
                for (int j = 0; j < 8; ++j)
                    xv[j] = xp[(size_t)(kc * 32 + lg * 8 + j) * n + pt * 16];
                FragU fu;
#pragma unroll
                for (int i = 0; i < 4; ++i)
                    fu.u[i] = pack2(xv[2 * i], xv[2 * i + 1]);
                bx[pt][kc] = fu.v;
            }

#pragma unroll
        for (int h = 0; h < 4; ++h) {
#pragma unroll
            for (int rt = 0; rt < 2; ++rt) {
                // W A-fragments (L1/L2-resident)
                s16x8 ak0 = *(const s16x8*)&Wb4[((2 * h + rt) * 2 + 0) * 64 + l];
                s16x8 ak1 = *(const s16x8*)&Wb4[((2 * h + rt) * 2 + 1) * 64 + l];
                s16x8 av0 = *(const s16x8*)&Wb4[((8 + 2 * h + rt) * 2 + 0) * 64 + l];
                s16x8 av1 = *(const s16x8*)&Wb4[((8 + 2 * h + rt) * 2 + 1) * 64 + l];
#pragma unroll
                for (int pt = 0; pt < 2; ++pt) {
                    f32x4 z = zero4;
                    z = __builtin_amdgcn_mfma_f32_16x16x32_bf16(ak0, bx[pt][0], z, 0, 0, 0);
                    z = __builtin_amdgcn_mfma_f32_16x16x32_bf16(ak1, bx[pt][1], z, 0, 0, 0);
                    f32x4 z2 = zero4;
                    z2 = __builtin_amdgcn_mfma_f32_16x16x32_bf16(av0, bx[pt][0], z2, 0, 0, 0);
                    z2 = __builtin_amdgcn_mfma_f32_16x16x32_bf16(av1, bx[pt][1], z2, 0, 0, 0);
                    // exp + restage to per-wave [row][pos] (80B-padded rows)
                    const int row0 = rt * 16 + lg * 4;
                    const int pos = pt * 16 + l15;
                    {
                        unsigned short e0 = f2b(__expf(z[0]));
                        unsigned short e1 = f2b(__expf(z[1]));
                        unsigned short e2 = f2b(__expf(z[2]));
                        unsigned short e3 = f2b(__expf(z[3]));
                        unsigned short* bp = &EKVs[w][row0 * 40 + pos];
                        bp[0]   = e0;
                        bp[40]  = e1;
                        bp[80]  = e2;
                        bp[120] = e3;
                        // accumulate the ROUNDED values (consistent with numerator operand)
                        sacc[h][rt][0] += b2f(e0);
                        sacc[h][rt][1] += b2f(e1);
                        sacc[h][rt][2] += b2f(e2);
                        sacc[h][rt][3] += b2f(e3);
                    }
                    {
                        unsigned short* bp = &EKVs[w][1280 + row0 * 40 + pos];
                        bp[0]   = f2b(z2[0]);
                        bp[40]  = f2b(z2[1]);
                        bp[80]  = f2b(z2[2]);
                        bp[120] = f2b(z2[3]);
                    }
                }
            }
            // context: C_h += EK (32xK32) @ V^T (K32x32)  (same-wave LDS, in-order DS pipe)
            s16x8 ea[2], vbf[2];
#pragma unroll
            for (int kt = 0; kt < 2; ++kt)
                ea[kt] = *(const s16x8*)&EKVs[w][(kt * 16 + l15) * 40 + lg * 8];
#pragma unroll
            for (int vt = 0; vt < 2; ++vt)
                vbf[vt] = *(const s16x8*)&EKVs[w][1280 + (vt * 16 + l15) * 40 + lg * 8];
#pragma unroll
            for (int kt = 0; kt < 2; ++kt)
#pragma unroll
                for (int vt = 0; vt < 2; ++vt)
                    ctx[h][kt][vt] = __builtin_amdgcn_mfma_f32_16x16x32_bf16(
                        ea[kt], vbf[vt], ctx[h][kt][vt], 0, 0, 0);
        }
    }

    // ---- cross-wave reduce, write per-block partials (EKVs aliased: 4224 of 5120 floats) ----
    float* Xf = (float*)&EKVs[0][0];
    float* Sf = Xf + 4096;
    float* Pb = P + (size_t)(b * gridDim.x + blockIdx.x) * 4224;
#pragma unroll
    for (int h = 0; h < 4; ++h) {
        __syncthreads();   // (h=0): all waves done with EKV reads; (h>0): done reading Xf
#pragma unroll
        for (int kt = 0; kt < 2; ++kt)
#pragma unroll
            for (int vt = 0; vt < 2; ++vt)
#pragma unroll
                for (int r = 0; r < 4; ++r) {
                    int d = kt * 16 + lg * 4 + r, e = vt * 16 + l15;
                    Xf[w * 1024 + d * 32 + e] = ctx[h][kt][vt][r];
                }
#pragma unroll
        for (int rt = 0; rt < 2; ++rt)
#pragma unroll
            for (int r = 0; r < 4; ++r) {
                float s = sacc[h][rt][r];
                s += __shfl_xor(s, 1); s += __shfl_xor(s, 2);
                s += __shfl_xor(s, 4); s += __shfl_xor(s, 8);
                if (l15 == 0) Sf[w * 32 + rt * 16 + lg * 4 + r] = s;
            }
        __syncthreads();
        for (int i = tid; i < 1024; i += 256)
            Pb[h * 1056 + i] = Xf[i] + Xf[1024 + i] + Xf[2048 + i] + Xf[3072 + i];
        if (tid < 32)
            Pb[h * 1056 + 1024 + tid] = Sf[tid] + Sf[32 + tid] + Sf[64 + tid] + Sf[96 + tid];
    }
}

// K2a: slot-sliced partial reduce: P[b][slot][4224] -> P2[b][16][4224]
__global__ __launch_bounds__(256) void reduce_p1(
    const float* __restrict__ P, float* __restrict__ P2, int nblk)
{
    const int idx = blockIdx.x * 256 + threadIdx.x;
    if (idx >= 4224) return;
    const int b = blockIdx.z, sz = blockIdx.y;
    float acc = 0.f;
    for (int slot = sz; slot < nblk; slot += 16)
        acc += P[((size_t)(b * nblk + slot)) * 4224 + idx];
    P2[((size_t)(b * 16 + sz)) * 4224 + idx] = acc;
}

// K2b: final reduce -> R[b][4224]
__global__ __launch_bounds__(256) void reduce_p2(
    const float* __restrict__ P2, float* __restrict__ R)
{
    const int idx = blockIdx.x * 256 + threadIdx.x;
    if (idx >= 4224) return;
    const int b = blockIdx.y;
    float acc = 0.f;
#pragma unroll
    for (int s = 0; s < 16; ++s)
        acc += P2[((size_t)(b * 16 + s)) * 4224 + idx];
    R[b * 4224 + idx] = acc;
}

// K3: build per-batch transposed 64x64 matrix Mt[c][o]
__global__ __launch_bounds__(256) void build_M(
    const float* __restrict__ R, const float* __restrict__ Wout,
    const float* __restrict__ Wqkv, float* __restrict__ Mt)
{
    __shared__ float ctx[4096];
    __shared__ float Ash[8192];
    const int b = blockIdx.x;
    const int tid = threadIdx.x;
    for (int i = tid; i < 4096; i += 256) {
        const int h = i >> 10, rr = i & 1023, d = rr >> 5, e = rr & 31;
        ctx[i] = R[b * 4224 + h * 1056 + d * 32 + e] /
                 R[b * 4224 + h * 1056 + 1024 + d];
    }
    __syncthreads();
    for (int i = tid; i < 8192; i += 256) {
        const int o = i >> 7, m = i & 127, h = m >> 5, d = m & 31;
        float acc = 0.f;
#pragma unroll
        for (int e = 0; e < 32; ++e)
            acc += Wout[o * 128 + h * 32 + e] * ctx[h * 1024 + d * 32 + e];
        Ash[i] = acc;
    }
    __syncthreads();
    const float scale = 0.17677669529663687f;
    for (int i = tid; i < 4096; i += 256) {
        const int o = i >> 6, c = i & 63;
        float acc = 0.f;
#pragma unroll
        for (int m = 0; m < 128; ++m)
            acc += Ash[o * 128 + m] * Wqkv[m * 64 + c];
        Mt[b * 4096 + c * 64 + o] = acc * scale;   // transposed store
    }
}

// K4: y[b,o,p] = sum_c Mt[c][o] x[b,c,p] + b_out[o]
__global__ __launch_bounds__(256, 4) void final_proj(
    const float* __restrict__ x, const float* __restrict__ Mt,
    const float* __restrict__ bout, float* __restrict__ y, int n)
{
    const int b = blockIdx.y;
    const int p = blockIdx.x * 256 + threadIdx.x;
    const float* xb = x + (size_t)b * CIN * n + p;
    const float* M = Mt + b * 4096;
    float acc[64];
#pragma unroll
    for (int o = 0; o < 64; ++o) acc[o] = bout[o];
    for (int c = 0; c < 64; ++c) {
        const float xv = xb[(size_t)c * n];
        const float* Mr = M + c * 64;
#pragma unroll
        for (int o = 0; o < 64; ++o) acc[o] += Mr[o] * xv;
    }
    float* yb = y + (size_t)b * CIN * n + p;
#pragma unroll
    for (int o = 0; o < 64; ++o) yb[(size_t)o * n] = acc[o];
}

extern "C" void kernel_launch(void* const* d_in, const int* in_sizes, int n_in,
                              void* d_out, int out_size, void* d_ws, size_t ws_size,
                              hipStream_t stream) {
    const float* x    = (const float*)d_in[0];
    const float* Wqkv = (const float*)d_in[1];
    const float* Wout = (const float*)d_in[2];
    const float* bout = (const float*)d_in[3];
    float* y = (float*)d_out;

    const int n = in_sizes[0] / 128;   // 110592
    const int nch = n / NP;            // 864

    // ws-adaptive partial-slot count
    int BLKX = 432;
    for (;;) {
        size_t need = 32768 + (size_t)2 * BLKX * 4224 * 4   // P
                    + (size_t)2 * 16 * 4224 * 4             // P2
                    + 2 * 4224 * 4 + 2 * 4096 * 4;          // R, Mt
        if (need <= ws_size || BLKX <= 64) break;
        BLKX = (BLKX == 432) ? 256 : (BLKX >> 1);
    }
    unsigned short* Wb = (unsigned short*)d_ws;                  // 32 KiB
    float* P  = (float*)((char*)d_ws + 32768);
    float* P2 = P + (size_t)2 * BLKX * 4224;
    float* R  = P2 + (size_t)2 * 16 * 4224;
    float* Mt = R + 2 * 4224;

    prep_w<<<8, 256, 0, stream>>>(Wqkv, Wb);
    lin_attn_ctx<<<dim3(BLKX, 2), 256, 0, stream>>>(x, Wb, P, n, nch);
    reduce_p1<<<dim3(17, 16, 2), 256, 0, stream>>>(P, P2, BLKX);
    reduce_p2<<<dim3(17, 2), 256, 0, stream>>>(P2, R);
    build_M<<<2, 256, 0, stream>>>(R, Wout, Wqkv, Mt);
    final_proj<<<dim3(n / 256, 2), 256, 0, stream>>>(x, Mt, bout, y, n);
}

// Round 10
// 115.470 us; speedup vs baseline: 1.5710x; 1.2740x over previous
//
#include <hip/hip_runtime.h>
#include <math.h>

#define CIN 64
#define NP 128

typedef float f32x4 __attribute__((ext_vector_type(4)));
typedef short s16x8 __attribute__((ext_vector_type(8)));

union FragU { s16x8 v; unsigned u[4]; };

static __device__ __forceinline__ unsigned short f2b(float f) {
    unsigned u = __builtin_bit_cast(unsigned, f);
    unsigned r = (u + 0x7FFFu + ((u >> 16) & 1u)) >> 16;   // RNE (proven R1/R2/R5/R8)
    return (unsigned short)r;
}
static __device__ __forceinline__ float b2f(unsigned short h) {
    unsigned u = ((unsigned)h) << 16;
    return __builtin_bit_cast(float, u);
}
// pack two f32 -> bf16x2 word, software RNE — NOT v_cvt_pk (R6: raw instr != RNE)
static __device__ __forceinline__ unsigned pack2(float lo, float hi) {
    return (unsigned)f2b(lo) | ((unsigned)f2b(hi) << 16);
}

// K0: pack W_k, W_v (rows 128..383 of Wqkv) into bf16 MFMA A-fragment tiles.
__global__ __launch_bounds__(256) void prep_w(const float* __restrict__ Wqkv,
                                              unsigned short* __restrict__ Wb) {
    int e0 = (blockIdx.x * 256 + threadIdx.x) * 8;   // < 16384
    int lane = (e0 >> 3) & 63;
    int kc = (e0 >> 9) & 1;
    int t = e0 >> 10;
    int row = 128 + t * 16 + (lane & 15);
    int c0 = kc * 32 + (lane >> 4) * 8;
    for (int j = 0; j < 8; ++j)
        Wb[e0 + j] = f2b(Wqkv[row * 64 + c0 + j]);
}

// K1: fused kv-projection (MFMA) + exp + context accumulation (MFMA).
// blockIdx.z selects a 2-head group: halves persistent accumulators
// (ctx 64->32, sacc 32->16 VGPR) so peak live state fits the compiler's
// 128-reg choice with NO spill (R5/R8/R9: spill round-trip was ~75-230MB).
// x is read once per head-group; second stream is L3-resident (56.6MB << 256MB).
__global__ __launch_bounds__(256, 2) void lin_attn_ctx(
    const float* __restrict__ x, const unsigned short* __restrict__ Wb,
    float* __restrict__ P, int n, int nch)
{
    __shared__ __align__(16) unsigned short EKVs[4][2560];  // 20 KiB: per-wave EK | V (80B rows)

    const int tid = threadIdx.x;
    const int l = tid & 63;
    const int w = tid >> 6;
    const int b = blockIdx.y;
    const int hg = blockIdx.z;           // head group: heads {2*hg, 2*hg+1}
    const int l15 = l & 15, lg = l >> 4;
    const uint4* Wb4 = (const uint4*)Wb;

    f32x4 zero4 = {0.f, 0.f, 0.f, 0.f};
    f32x4 ctx[2][2][2];
    float sacc[2][2][4];
#pragma unroll
    for (int hh = 0; hh < 2; ++hh)
#pragma unroll
        for (int a = 0; a < 2; ++a) {
#pragma unroll
            for (int c2 = 0; c2 < 2; ++c2) ctx[hh][a][c2] = zero4;
#pragma unroll
            for (int r = 0; r < 4; ++r) sacc[hh][a][r] = 0.f;
        }

    const float* xw = x + (size_t)b * CIN * n;

    for (int ch = blockIdx.x; ch < nch; ch += gridDim.x) {
        // ---- direct global -> B-fragment loads, pack immediately ----
        const float* xp = xw + ch * NP + w * 32 + l15;
        s16x8 bx[2][2];
#pragma unroll
        for (int pt = 0; pt < 2; ++pt)
#pragma unroll
            for (int kc = 0; kc < 2; ++kc) {
                float xv[8];
#pragma unroll
                for (int j = 0; j < 8; ++j)
                    xv[j] = xp[(size_t)(kc * 32 + lg * 8 + j) * n + pt * 16];
                FragU fu;
#pragma unroll
                for (int i = 0; i < 4; ++i)
                    fu.u[i] = pack2(xv[2 * i], xv[2 * i + 1]);
                bx[pt][kc] = fu.v;
            }

#pragma unroll
        for (int hh = 0; hh < 2; ++hh) {
            const int h = hg * 2 + hh;
#pragma unroll
            for (int rt = 0; rt < 2; ++rt) {
                // W A-fragments (L1/L2-resident)
                s16x8 ak0 = *(const s16x8*)&Wb4[((2 * h + rt) * 2 + 0) * 64 + l];
                s16x8 ak1 = *(const s16x8*)&Wb4[((2 * h + rt) * 2 + 1) * 64 + l];
                s16x8 av0 = *(const s16x8*)&Wb4[((8 + 2 * h + rt) * 2 + 0) * 64 + l];
                s16x8 av1 = *(const s16x8*)&Wb4[((8 + 2 * h + rt) * 2 + 1) * 64 + l];
#pragma unroll
                for (int pt = 0; pt < 2; ++pt) {
                    f32x4 z = zero4;
                    z = __builtin_amdgcn_mfma_f32_16x16x32_bf16(ak0, bx[pt][0], z, 0, 0, 0);
                    z = __builtin_amdgcn_mfma_f32_16x16x32_bf16(ak1, bx[pt][1], z, 0, 0, 0);
                    f32x4 z2 = zero4;
                    z2 = __builtin_amdgcn_mfma_f32_16x16x32_bf16(av0, bx[pt][0], z2, 0, 0, 0);
                    z2 = __builtin_amdgcn_mfma_f32_16x16x32_bf16(av1, bx[pt][1], z2, 0, 0, 0);
                    // exp + restage to per-wave [row][pos] (80B-padded rows)
                    const int row0 = rt * 16 + lg * 4;
                    const int pos = pt * 16 + l15;
                    {
                        unsigned short e0 = f2b(__expf(z[0]));
                        unsigned short e1 = f2b(__expf(z[1]));
                        unsigned short e2 = f2b(__expf(z[2]));
                        unsigned short e3 = f2b(__expf(z[3]));
                        unsigned short* bp = &EKVs[w][row0 * 40 + pos];
                        bp[0]   = e0;
                        bp[40]  = e1;
                        bp[80]  = e2;
                        bp[120] = e3;
                        // accumulate the ROUNDED values (consistent with numerator operand)
                        sacc[hh][rt][0] += b2f(e0);
                        sacc[hh][rt][1] += b2f(e1);
                        sacc[hh][rt][2] += b2f(e2);
                        sacc[hh][rt][3] += b2f(e3);
                    }
                    {
                        unsigned short* bp = &EKVs[w][1280 + row0 * 40 + pos];
                        bp[0]   = f2b(z2[0]);
                        bp[40]  = f2b(z2[1]);
                        bp[80]  = f2b(z2[2]);
                        bp[120] = f2b(z2[3]);
                    }
                }
            }
            // context: C_h += EK (32xK32) @ V^T (K32x32)  (same-wave LDS, in-order DS pipe)
            s16x8 ea[2], vbf[2];
#pragma unroll
            for (int kt = 0; kt < 2; ++kt)
                ea[kt] = *(const s16x8*)&EKVs[w][(kt * 16 + l15) * 40 + lg * 8];
#pragma unroll
            for (int vt = 0; vt < 2; ++vt)
                vbf[vt] = *(const s16x8*)&EKVs[w][1280 + (vt * 16 + l15) * 40 + lg * 8];
#pragma unroll
            for (int kt = 0; kt < 2; ++kt)
#pragma unroll
                for (int vt = 0; vt < 2; ++vt)
                    ctx[hh][kt][vt] = __builtin_amdgcn_mfma_f32_16x16x32_bf16(
                        ea[kt], vbf[vt], ctx[hh][kt][vt], 0, 0, 0);
        }
    }

    // ---- cross-wave reduce, write per-block partials ----
    // Two hg-blocks share one P slot, writing disjoint head halves.
    float* Xf = (float*)&EKVs[0][0];
    float* Sf = Xf + 4096;
    float* Pb = P + (size_t)(b * gridDim.x + blockIdx.x) * 4224;
#pragma unroll
    for (int hh = 0; hh < 2; ++hh) {
        const int h = hg * 2 + hh;
        __syncthreads();   // (hh=0): all waves done with EKV reads; (hh=1): done reading Xf
#pragma unroll
        for (int kt = 0; kt < 2; ++kt)
#pragma unroll
            for (int vt = 0; vt < 2; ++vt)
#pragma unroll
                for (int r = 0; r < 4; ++r) {
                    int d = kt * 16 + lg * 4 + r, e = vt * 16 + l15;
                    Xf[w * 1024 + d * 32 + e] = ctx[hh][kt][vt][r];
                }
#pragma unroll
        for (int rt = 0; rt < 2; ++rt)
#pragma unroll
            for (int r = 0; r < 4; ++r) {
                float s = sacc[hh][rt][r];
                s += __shfl_xor(s, 1); s += __shfl_xor(s, 2);
                s += __shfl_xor(s, 4); s += __shfl_xor(s, 8);
                if (l15 == 0) Sf[w * 32 + rt * 16 + lg * 4 + r] = s;
            }
        __syncthreads();
        for (int i = tid; i < 1024; i += 256)
            Pb[h * 1056 + i] = Xf[i] + Xf[1024 + i] + Xf[2048 + i] + Xf[3072 + i];
        if (tid < 32)
            Pb[h * 1056 + 1024 + tid] = Sf[tid] + Sf[32 + tid] + Sf[64 + tid] + Sf[96 + tid];
    }
}

// K2a: slot-sliced partial reduce: P[b][slot][4224] -> P2[b][16][4224]
__global__ __launch_bounds__(256) void reduce_p1(
    const float* __restrict__ P, float* __restrict__ P2, int nblk)
{
    const int idx = blockIdx.x * 256 + threadIdx.x;
    if (idx >= 4224) return;
    const int b = blockIdx.z, sz = blockIdx.y;
    float acc = 0.f;
    for (int slot = sz; slot < nblk; slot += 16)
        acc += P[((size_t)(b * nblk + slot)) * 4224 + idx];
    P2[((size_t)(b * 16 + sz)) * 4224 + idx] = acc;
}

// K2b: final reduce -> R[b][4224]
__global__ __launch_bounds__(256) void reduce_p2(
    const float* __restrict__ P2, float* __restrict__ R)
{
    const int idx = blockIdx.x * 256 + threadIdx.x;
    if (idx >= 4224) return;
    const int b = blockIdx.y;
    float acc = 0.f;
#pragma unroll
    for (int s = 0; s < 16; ++s)
        acc += P2[((size_t)(b * 16 + s)) * 4224 + idx];
    R[b * 4224 + idx] = acc;
}

// K3: build per-batch transposed 64x64 matrix Mt[c][o]
__global__ __launch_bounds__(256) void build_M(
    const float* __restrict__ R, const float* __restrict__ Wout,
    const float* __restrict__ Wqkv, float* __restrict__ Mt)
{
    __shared__ float ctx[4096];
    __shared__ float Ash[8192];
    const int b = blockIdx.x;
    const int tid = threadIdx.x;
    for (int i = tid; i < 4096; i += 256) {
        const int h = i >> 10, rr = i & 1023, d = rr >> 5, e = rr & 31;
        ctx[i] = R[b * 4224 + h * 1056 + d * 32 + e] /
                 R[b * 4224 + h * 1056 + 1024 + d];
    }
    __syncthreads();
    for (int i = tid; i < 8192; i += 256) {
        const int o = i >> 7, m = i & 127, h = m >> 5, d = m & 31;
        float acc = 0.f;
#pragma unroll
        for (int e = 0; e < 32; ++e)
            acc += Wout[o * 128 + h * 32 + e] * ctx[h * 1024 + d * 32 + e];
        Ash[i] = acc;
    }
    __syncthreads();
    const float scale = 0.17677669529663687f;
    for (int i = tid; i < 4096; i += 256) {
        const int o = i >> 6, c = i & 63;
        float acc = 0.f;
#pragma unroll
        for (int m = 0; m < 128; ++m)
            acc += Ash[o * 128 + m] * Wqkv[m * 64 + c];
        Mt[b * 4096 + c * 64 + o] = acc * scale;   // transposed store
    }
}

// K4: y[b,o,p] = sum_c Mt[c][o] x[b,c,p] + b_out[o]
__global__ __launch_bounds__(256, 4) void final_proj(
    const float* __restrict__ x, const float* __restrict__ Mt,
    const float* __restrict__ bout, float* __restrict__ y, int n)
{
    const int b = blockIdx.y;
    const int p = blockIdx.x * 256 + threadIdx.x;
    const float* xb = x + (size_t)b * CIN * n + p;
    const float* M = Mt + b * 4096;
    float acc[64];
#pragma unroll
    for (int o = 0; o < 64; ++o) acc[o] = bout[o];
    for (int c = 0; c < 64; ++c) {
        const float xv = xb[(size_t)c * n];
        const float* Mr = M + c * 64;
#pragma unroll
        for (int o = 0; o < 64; ++o) acc[o] += Mr[o] * xv;
    }
    float* yb = y + (size_t)b * CIN * n + p;
#pragma unroll
    for (int o = 0; o < 64; ++o) yb[(size_t)o * n] = acc[o];
}

extern "C" void kernel_launch(void* const* d_in, const int* in_sizes, int n_in,
                              void* d_out, int out_size, void* d_ws, size_t ws_size,
                              hipStream_t stream) {
    const float* x    = (const float*)d_in[0];
    const float* Wqkv = (const float*)d_in[1];
    const float* Wout = (const float*)d_in[2];
    const float* bout = (const float*)d_in[3];
    float* y = (float*)d_out;

    const int n = in_sizes[0] / 128;   // 110592
    const int nch = n / NP;            // 864

    // ws-adaptive partial-slot count
    int BLKX = 432;
    for (;;) {
        size_t need = 32768 + (size_t)2 * BLKX * 4224 * 4   // P
                    + (size_t)2 * 16 * 4224 * 4             // P2
                    + 2 * 4224 * 4 + 2 * 4096 * 4;          // R, Mt
        if (need <= ws_size || BLKX <= 64) break;
        BLKX = (BLKX == 432) ? 256 : (BLKX >> 1);
    }
    unsigned short* Wb = (unsigned short*)d_ws;                  // 32 KiB
    float* P  = (float*)((char*)d_ws + 32768);
    float* P2 = P + (size_t)2 * BLKX * 4224;
    float* R  = P2 + (size_t)2 * 16 * 4224;
    float* Mt = R + 2 * 4224;

    prep_w<<<8, 256, 0, stream>>>(Wqkv, Wb);
    lin_attn_ctx<<<dim3(BLKX, 2, 2), 256, 0, stream>>>(x, Wb, P, n, nch);
    reduce_p1<<<dim3(17, 16, 2), 256, 0, stream>>>(P, P2, BLKX);
    reduce_p2<<<dim3(17, 2), 256, 0, stream>>>(P2, R);
    build_M<<<2, 256, 0, stream>>>(R, Wout, Wqkv, Mt);
    final_proj<<<dim3(n / 256, 2), 256, 0, stream>>>(x, Mt, bout, y, n);
}